// Round 27
// baseline (92.532 us; speedup 1.0000x reference)
//
#include <hip/hip_runtime.h>
#include <hip/hip_bf16.h>

// Problem constants
#define NN 64
#define BB 256
#define DD 1792
#define KK 35
#define PP 10
#define DQ 448          // D / 4 (float4s per row)
#define GR 4            // rows per group (16 groups of 4)
#define NGRP 28         // 16-lane groups per 448-thread block

typedef float fx4 __attribute__((ext_vector_type(4)));

// PROVEN (R2-R8): 4-step row_shr DPP chain, bound_ctrl:0.
// Leaves the 16-lane-group sum in lane 15 of each group.
__device__ __forceinline__ float group16_sum_dpp(float x) {
    asm("v_add_f32_dpp %0, %0, %0 row_shr:1 row_mask:0xf bank_mask:0xf bound_ctrl:0" : "+v"(x));
    asm("v_add_f32_dpp %0, %0, %0 row_shr:2 row_mask:0xf bank_mask:0xf bound_ctrl:0" : "+v"(x));
    asm("v_add_f32_dpp %0, %0, %0 row_shr:4 row_mask:0xf bank_mask:0xf bound_ctrl:0" : "+v"(x));
    asm("v_add_f32_dpp %0, %0, %0 row_shr:8 row_mask:0xf bank_mask:0xf bound_ctrl:0" : "+v"(x));
    return x;
}

// ---------------------------------------------------------------------------
// K1: Gf = gamma * W_net; sG[p] = sum(Gf[p]); zc[p] = dot(beta,Wnet[p]) + b_net[p]
// ---------------------------------------------------------------------------
__global__ void prep_gf(const float* __restrict__ gamma, const float* __restrict__ beta,
                        const float* __restrict__ Wnet, const float* __restrict__ bnet,
                        float* __restrict__ GF, float* __restrict__ SG, float* __restrict__ ZC) {
    const int p = blockIdx.x;
    const int tid = threadIdx.x;
    float sg = 0.f, sb = 0.f;
#pragma unroll
    for (int j = 0; j < 7; ++j) {
        int d = j * 256 + tid;
        float wv = Wnet[p * DD + d];
        float g = gamma[d] * wv;
        GF[p * DD + d] = g;
        sg += g;
        sb += beta[d] * wv;
    }
#pragma unroll
    for (int off = 32; off > 0; off >>= 1) {
        sg += __shfl_xor(sg, off);
        sb += __shfl_xor(sb, off);
    }
    __shared__ float rs[4][2];
    if ((tid & 63) == 0) { rs[tid >> 6][0] = sg; rs[tid >> 6][1] = sb; }
    __syncthreads();
    if (tid == 0) {
        float a = 0.f, c = 0.f;
#pragma unroll
        for (int w = 0; w < 4; ++w) { a += rs[w][0]; c += rs[w][1]; }
        SG[p] = a;
        ZC[p] = c + bnet[p];
    }
}

// ---------------------------------------------------------------------------
// K2: bank[b][r] = dot(task[b], Wtok[r]) + btok[r]; ptok[b][d] likewise.
// ---------------------------------------------------------------------------
__global__ void prep_bank(const float* __restrict__ task,
                          const float* __restrict__ Wtok, const float* __restrict__ btok,
                          const float* __restrict__ Wptok, const float* __restrict__ bptok,
                          float* __restrict__ bank, float* __restrict__ ptok) {
    __shared__ float ti[32 * KK];
    const int tid = threadIdx.x;
    const int b0 = blockIdx.y * 32;
    for (int i = tid; i < 32 * KK; i += 256) ti[i] = task[b0 * KK + i];

    const int r = blockIdx.x * 256 + tid;
    const bool isbank = (r < PP * DD);
    const int rr = isbank ? r : (r - PP * DD);
    const float* __restrict__ W = isbank ? Wtok : Wptok;
    const float bias = isbank ? btok[r] : bptok[rr];

    float w[KK];
#pragma unroll
    for (int k = 0; k < KK; ++k) w[k] = W[rr * KK + k];

    __syncthreads();
#pragma unroll 1
    for (int bb = 0; bb < 32; ++bb) {
        float acc = bias;
#pragma unroll
        for (int k = 0; k < KK; ++k) acc = fmaf(ti[bb * KK + k], w[k], acc);
        const int b = b0 + bb;
        if (isbank) bank[b * (PP * DD) + r] = acc;
        else        ptok[b * DD + rr]       = acc;
    }
}

// ---------------------------------------------------------------------------
// K3 (fused_amort): ONE block per b (256 blocks), 448 threads. The L2-
// amortization kernel: loops are p-OUTER / r-INNER so each gf[p]/bk[p]
// operand is fetched ONCE PER 4-ROW GROUP instead of once per row ->
// gf/bk L2 traffic drops 4x (2.3 GB -> 0.57 GB per dispatch), taking the
// per-XCD L2 read pipe (the diagnosed saturated resource) off the
// critical path. 16 groups of GR=4 rows; ping-pong x buffers; t = x+ptk
// computed in place (phase 2 recovers x = t-ptk); raw lgkm-only barriers;
// NT out-stores.
// ---------------------------------------------------------------------------
__global__ __launch_bounds__(448, 1) void fused_amort(
    const float* __restrict__ X, const float* __restrict__ BANK,
    const float* __restrict__ PTOK, const float* __restrict__ GF,
    const float* __restrict__ SG, const float* __restrict__ ZC,
    float* __restrict__ OUT) {
    const int tid = threadIdx.x;
    const int b = blockIdx.x;

    const float4* __restrict__ X4 = (const float4*)X;
    const float4* __restrict__ B4 = (const float4*)BANK;
    const float4* __restrict__ G4 = (const float4*)GF;
    const float4* __restrict__ P4 = (const float4*)PTOK;
    fx4* __restrict__ OO = (fx4*)OUT;

    __shared__ float red[2][GR][NGRP][12];   // 10752 B
    __shared__ float wlds[2][GR][PP];        //   320 B

    const float4 ptk = P4[(size_t)b * DQ + tid];

    const bool writer = ((tid & 15) == 15);
    const int g16 = tid >> 4;
    const size_t rowstr = (size_t)BB * DQ;
    const size_t base = (size_t)b * DQ + tid;

    float4 xa[GR], xb[GR];

#define BURST(XN, GN)                                                              \
    {                                                                              \
        _Pragma("unroll")                                                          \
        for (int r = 0; r < GR; ++r)                                               \
            XN[r] = X4[(size_t)((GN) * GR + r) * rowstr + base];                   \
        __builtin_amdgcn_sched_barrier(0);                                         \
    }

#define BARRIER_RAW()                                                              \
    asm volatile("s_waitcnt lgkmcnt(0)" ::: "memory");                             \
    __builtin_amdgcn_sched_barrier(0);                                             \
    __builtin_amdgcn_s_barrier();                                                  \
    __builtin_amdgcn_sched_barrier(0);

// p-OUTER / r-INNER: each gfp fetched once per 4-row group.
#define PHASE1(XC, RB)                                                             \
    {                                                                              \
        _Pragma("unroll")                                                          \
        for (int r = 0; r < GR; ++r) {                                             \
            XC[r].x += ptk.x; XC[r].y += ptk.y;                                    \
            XC[r].z += ptk.z; XC[r].w += ptk.w;                                    \
        }                                                                          \
        float s1[GR], s2[GR], a[GR][PP];                                           \
        _Pragma("unroll")                                                          \
        for (int r = 0; r < GR; ++r) {                                             \
            s1[r] = XC[r].x + XC[r].y + XC[r].z + XC[r].w;                         \
            float q = XC[r].x * XC[r].x;                                           \
            q = fmaf(XC[r].y, XC[r].y, q);                                         \
            q = fmaf(XC[r].z, XC[r].z, q);                                         \
            q = fmaf(XC[r].w, XC[r].w, q);                                         \
            s2[r] = q;                                                             \
        }                                                                          \
        _Pragma("unroll")                                                          \
        for (int p = 0; p < PP; ++p) {                                             \
            const float4 gfp = G4[(size_t)p * DQ + tid];                           \
            _Pragma("unroll")                                                      \
            for (int r = 0; r < GR; ++r) {                                         \
                float v = XC[r].x * gfp.x;                                         \
                v = fmaf(XC[r].y, gfp.y, v);                                       \
                v = fmaf(XC[r].z, gfp.z, v);                                       \
                v = fmaf(XC[r].w, gfp.w, v);                                       \
                a[r][p] = v;                                                       \
            }                                                                      \
        }                                                                          \
        _Pragma("unroll")                                                          \
        for (int r = 0; r < GR; ++r) {                                             \
            s1[r] = group16_sum_dpp(s1[r]);                                        \
            s2[r] = group16_sum_dpp(s2[r]);                                        \
            _Pragma("unroll")                                                      \
            for (int p = 0; p < PP; ++p) a[r][p] = group16_sum_dpp(a[r][p]);       \
            if (writer) {                                                          \
                float4* dst = (float4*)&red[RB][r][g16][0];                        \
                dst[0] = make_float4(s1[r], s2[r], a[r][0], a[r][1]);              \
                dst[1] = make_float4(a[r][2], a[r][3], a[r][4], a[r][5]);          \
                dst[2] = make_float4(a[r][6], a[r][7], a[r][8], a[r][9]);          \
            }                                                                      \
        }                                                                          \
    }

#define FINALIZE(RB)                                                               \
    if (tid < GR * 16) {                                                           \
        const int row = tid >> 4;                                                  \
        const int v = tid & 15;                                                    \
        float f = 0.f;                                                             \
        if (v < 12) {                                                              \
            _Pragma("unroll")                                                      \
            for (int q = 0; q < NGRP; ++q) f += red[RB][row][q][v];                \
        }                                                                          \
        const int bse = (tid & 63) & ~15;                                          \
        const float mu = __shfl(f, bse)     * (1.0f / (float)DD);                  \
        const float ms = __shfl(f, bse + 1) * (1.0f / (float)DD);                  \
        const float istd = rsqrtf(ms - mu * mu + 1e-5f);                           \
        if (v >= 2 && v < 12) {                                                    \
            const int p = v - 2;                                                   \
            const float z = istd * (f - mu * SG[p]) + ZC[p];                       \
            wlds[RB][row][p] = 1.0f / (1.0f + __expf(-z));                         \
        }                                                                          \
    }

// p-OUTER / r-INNER: each bkp fetched once per 4-row group. acc = t - ptk
// recovers x, then += w*bank.
#define PHASE2(XC, WB, GN)                                                         \
    {                                                                              \
        fx4 acc[GR];                                                               \
        _Pragma("unroll")                                                          \
        for (int r = 0; r < GR; ++r) {                                             \
            acc[r].x = XC[r].x - ptk.x; acc[r].y = XC[r].y - ptk.y;                \
            acc[r].z = XC[r].z - ptk.z; acc[r].w = XC[r].w - ptk.w;                \
        }                                                                          \
        _Pragma("unroll")                                                          \
        for (int p = 0; p < PP; ++p) {                                             \
            const float4 bkp = B4[((size_t)b * PP + p) * DQ + tid];                \
            _Pragma("unroll")                                                      \
            for (int r = 0; r < GR; ++r) {                                         \
                const float wv = wlds[WB][r][p];                                   \
                acc[r].x = fmaf(wv, bkp.x, acc[r].x);                              \
                acc[r].y = fmaf(wv, bkp.y, acc[r].y);                              \
                acc[r].z = fmaf(wv, bkp.z, acc[r].z);                              \
                acc[r].w = fmaf(wv, bkp.w, acc[r].w);                              \
            }                                                                      \
        }                                                                          \
        _Pragma("unroll")                                                          \
        for (int r = 0; r < GR; ++r)                                               \
            __builtin_nontemporal_store(acc[r],                                    \
                &OO[(size_t)((GN) * GR + r) * rowstr + base]);                     \
    }

    // ---- prologue ----
    BURST(xa, 0)

#pragma unroll 1
    for (int gp = 0; gp < 8; ++gp) {
        const int ge = 2 * gp;          // even group (data in xa)
        // even group
        BURST(xb, ge + 1)
        PHASE1(xa, 0)
        BARRIER_RAW()
        FINALIZE(0)
        BARRIER_RAW()
        PHASE2(xa, 0, ge)
        // odd group
        if (gp < 7) BURST(xa, ge + 2)
        PHASE1(xb, 1)
        BARRIER_RAW()
        FINALIZE(1)
        BARRIER_RAW()
        PHASE2(xb, 1, ge + 1)
    }

#undef PHASE2
#undef FINALIZE
#undef PHASE1
#undef BARRIER_RAW
#undef BURST
}

// ---------------------------------------------------------------------------
extern "C" void kernel_launch(void* const* d_in, const int* in_sizes, int n_in,
                              void* d_out, int out_size, void* d_ws, size_t ws_size,
                              hipStream_t stream) {
    const float* X     = (const float*)d_in[0];
    const float* task  = (const float*)d_in[1];
    const float* Wtok  = (const float*)d_in[2];
    const float* btok  = (const float*)d_in[3];
    const float* Wptok = (const float*)d_in[4];
    const float* bptok = (const float*)d_in[5];
    const float* gamma = (const float*)d_in[6];
    const float* beta  = (const float*)d_in[7];
    const float* Wnet  = (const float*)d_in[8];
    const float* bnet  = (const float*)d_in[9];
    float* out = (float*)d_out;

    float* ws = (float*)d_ws;
    float* bank = ws;                                  // B*P*D = 4,587,520
    float* ptok = bank + (size_t)BB * PP * DD;         // B*D   =   458,752
    float* GF   = ptok + (size_t)BB * DD;              // P*D   =    17,920
    float* SG   = GF + PP * DD;                        // P
    float* ZC   = SG + PP;                             // P

    prep_gf<<<PP, 256, 0, stream>>>(gamma, beta, Wnet, bnet, GF, SG, ZC);
    prep_bank<<<dim3(77, 8), 256, 0, stream>>>(task, Wtok, btok, Wptok, bptok, bank, ptok);
    fused_amort<<<BB, 448, 0, stream>>>(X, bank, ptok, GF, SG, ZC, out);
}

// Round 28
// 73.909 us; speedup vs baseline: 1.2520x; 1.2520x over previous
//
#include <hip/hip_runtime.h>
#include <hip/hip_bf16.h>

// Problem constants
#define NN 64
#define BB 256
#define DD 1792
#define KK 35
#define PP 10
#define DQ 448          // D / 4 (float4s per row)
#define GR 8            // rows per group
#define NGRP 28         // 16-lane groups per 448-thread block

typedef float fx4 __attribute__((ext_vector_type(4)));

// PROVEN (R2-R8): 4-step row_shr DPP chain, bound_ctrl:0.
// Leaves the 16-lane-group sum in lane 15 of each group.
__device__ __forceinline__ float group16_sum_dpp(float x) {
    asm("v_add_f32_dpp %0, %0, %0 row_shr:1 row_mask:0xf bank_mask:0xf bound_ctrl:0" : "+v"(x));
    asm("v_add_f32_dpp %0, %0, %0 row_shr:2 row_mask:0xf bank_mask:0xf bound_ctrl:0" : "+v"(x));
    asm("v_add_f32_dpp %0, %0, %0 row_shr:4 row_mask:0xf bank_mask:0xf bound_ctrl:0" : "+v"(x));
    asm("v_add_f32_dpp %0, %0, %0 row_shr:8 row_mask:0xf bank_mask:0xf bound_ctrl:0" : "+v"(x));
    return x;
}

// ---------------------------------------------------------------------------
// K1: Gf = gamma * W_net; sG[p] = sum(Gf[p]); zc[p] = dot(beta,Wnet[p]) + b_net[p]
// ---------------------------------------------------------------------------
__global__ void prep_gf(const float* __restrict__ gamma, const float* __restrict__ beta,
                        const float* __restrict__ Wnet, const float* __restrict__ bnet,
                        float* __restrict__ GF, float* __restrict__ SG, float* __restrict__ ZC) {
    const int p = blockIdx.x;
    const int tid = threadIdx.x;
    float sg = 0.f, sb = 0.f;
#pragma unroll
    for (int j = 0; j < 7; ++j) {
        int d = j * 256 + tid;
        float wv = Wnet[p * DD + d];
        float g = gamma[d] * wv;
        GF[p * DD + d] = g;
        sg += g;
        sb += beta[d] * wv;
    }
#pragma unroll
    for (int off = 32; off > 0; off >>= 1) {
        sg += __shfl_xor(sg, off);
        sb += __shfl_xor(sb, off);
    }
    __shared__ float rs[4][2];
    if ((tid & 63) == 0) { rs[tid >> 6][0] = sg; rs[tid >> 6][1] = sb; }
    __syncthreads();
    if (tid == 0) {
        float a = 0.f, c = 0.f;
#pragma unroll
        for (int w = 0; w < 4; ++w) { a += rs[w][0]; c += rs[w][1]; }
        SG[p] = a;
        ZC[p] = c + bnet[p];
    }
}

// ---------------------------------------------------------------------------
// K2: bank[b][r] = dot(task[b], Wtok[r]) + btok[r]; ptok[b][d] likewise.
// ---------------------------------------------------------------------------
__global__ void prep_bank(const float* __restrict__ task,
                          const float* __restrict__ Wtok, const float* __restrict__ btok,
                          const float* __restrict__ Wptok, const float* __restrict__ bptok,
                          float* __restrict__ bank, float* __restrict__ ptok) {
    __shared__ float ti[32 * KK];
    const int tid = threadIdx.x;
    const int b0 = blockIdx.y * 32;
    for (int i = tid; i < 32 * KK; i += 256) ti[i] = task[b0 * KK + i];

    const int r = blockIdx.x * 256 + tid;
    const bool isbank = (r < PP * DD);
    const int rr = isbank ? r : (r - PP * DD);
    const float* __restrict__ W = isbank ? Wtok : Wptok;
    const float bias = isbank ? btok[r] : bptok[rr];

    float w[KK];
#pragma unroll
    for (int k = 0; k < KK; ++k) w[k] = W[rr * KK + k];

    __syncthreads();
#pragma unroll 1
    for (int bb = 0; bb < 32; ++bb) {
        float acc = bias;
#pragma unroll
        for (int k = 0; k < KK; ++k) acc = fmaf(ti[bb * KK + k], w[k], acc);
        const int b = b0 + bb;
        if (isbank) bank[b * (PP * DD) + r] = acc;
        else        ptok[b * DD + rr]       = acc;
    }
}

// ---------------------------------------------------------------------------
// K3 (fused_pipe): ONE block per b (256 blocks). 448 threads. Best-known
// structure (R21, 73.9 us): per-b persistent regs (ptk/gf/bank), 8 groups
// of 8 rows, cross-group pipeline
//   BURST(g+1) -> PHASE1(g) -> BARRIER -> { FINALIZE(g) ; PHASE2(g-1) }
// (one raw lgkm-only barrier per group; finalize overlapped with previous
// group's apply; X triple-buffered in regs), nontemporal out-stores.
// ---------------------------------------------------------------------------
__global__ __launch_bounds__(448, 1) void fused_pipe(
    const float* __restrict__ X, const float* __restrict__ BANK,
    const float* __restrict__ PTOK, const float* __restrict__ GF,
    const float* __restrict__ SG, const float* __restrict__ ZC,
    float* __restrict__ OUT) {
    const int tid = threadIdx.x;
    const int b = blockIdx.x;

    const float4* __restrict__ X4 = (const float4*)X;
    const float4* __restrict__ B4 = (const float4*)BANK;
    const float4* __restrict__ G4 = (const float4*)GF;
    const float4* __restrict__ P4 = (const float4*)PTOK;
    fx4* __restrict__ OO = (fx4*)OUT;

    __shared__ float red[2][GR][NGRP][12];   // 21504 B
    __shared__ float wlds[2][GR][PP];        //   640 B

    // ---- persistent state: loaded once for the whole block ----
    const float4 ptk = P4[(size_t)b * DQ + tid];
    float4 gf[PP];
#pragma unroll
    for (int p = 0; p < PP; ++p) gf[p] = G4[(size_t)p * DQ + tid];
    float4 bk[PP];
#pragma unroll
    for (int p = 0; p < PP; ++p) bk[p] = B4[((size_t)b * PP + p) * DQ + tid];

    const bool writer = ((tid & 15) == 15);
    const int g16 = tid >> 4;

    float4 x0[GR], x1[GR], x2[GR];

#define BURST(XN, GN)                                                              \
    {                                                                              \
        _Pragma("unroll")                                                          \
        for (int r = 0; r < GR; ++r)                                               \
            XN[r] = X4[((size_t)((GN) * GR + r) * BB + b) * DQ + tid];             \
        __builtin_amdgcn_sched_barrier(0);                                         \
    }

#define BARRIER_RAW()                                                              \
    asm volatile("s_waitcnt lgkmcnt(0)" ::: "memory");                             \
    __builtin_amdgcn_sched_barrier(0);                                             \
    __builtin_amdgcn_s_barrier();                                                  \
    __builtin_amdgcn_sched_barrier(0);

#define PHASE1(XC, RB)                                                             \
    {                                                                              \
        _Pragma("unroll")                                                          \
        for (int r = 0; r < GR; ++r) {                                             \
            float4 t;                                                              \
            t.x = XC[r].x + ptk.x; t.y = XC[r].y + ptk.y;                          \
            t.z = XC[r].z + ptk.z; t.w = XC[r].w + ptk.w;                          \
            float s1 = t.x + t.y + t.z + t.w;                                      \
            float s2 = t.x * t.x;                                                  \
            s2 = fmaf(t.y, t.y, s2); s2 = fmaf(t.z, t.z, s2);                      \
            s2 = fmaf(t.w, t.w, s2);                                               \
            float a[PP];                                                           \
            _Pragma("unroll")                                                      \
            for (int p = 0; p < PP; ++p) {                                         \
                float v = t.x * gf[p].x;                                           \
                v = fmaf(t.y, gf[p].y, v);                                         \
                v = fmaf(t.z, gf[p].z, v);                                         \
                v = fmaf(t.w, gf[p].w, v);                                         \
                a[p] = v;                                                          \
            }                                                                      \
            s1 = group16_sum_dpp(s1);                                              \
            s2 = group16_sum_dpp(s2);                                              \
            _Pragma("unroll")                                                      \
            for (int p = 0; p < PP; ++p) a[p] = group16_sum_dpp(a[p]);             \
            if (writer) {                                                          \
                float4* dst = (float4*)&red[RB][r][g16][0];                        \
                dst[0] = make_float4(s1, s2, a[0], a[1]);                          \
                dst[1] = make_float4(a[2], a[3], a[4], a[5]);                      \
                dst[2] = make_float4(a[6], a[7], a[8], a[9]);                      \
            }                                                                      \
        }                                                                          \
    }

#define FINALIZE(RB)                                                               \
    if (tid < GR * 16) {                                                           \
        const int row = tid >> 4;                                                  \
        const int v = tid & 15;                                                    \
        float f = 0.f;                                                             \
        if (v < 12) {                                                              \
            _Pragma("unroll")                                                      \
            for (int q = 0; q < NGRP; ++q) f += red[RB][row][q][v];                \
        }                                                                          \
        const int bse = (tid & 63) & ~15;                                          \
        const float mu = __shfl(f, bse)     * (1.0f / (float)DD);                  \
        const float ms = __shfl(f, bse + 1) * (1.0f / (float)DD);                  \
        const float istd = rsqrtf(ms - mu * mu + 1e-5f);                           \
        if (v >= 2 && v < 12) {                                                    \
            const int p = v - 2;                                                   \
            const float z = istd * (f - mu * SG[p]) + ZC[p];                       \
            wlds[RB][row][p] = 1.0f / (1.0f + __expf(-z));                         \
        }                                                                          \
    }

#define PHASE2(XC, WB, GN)                                                         \
    {                                                                              \
        _Pragma("unroll")                                                          \
        for (int r = 0; r < GR; ++r) {                                             \
            float4 acc = XC[r];                                                    \
            _Pragma("unroll")                                                      \
            for (int p = 0; p < PP; ++p) {                                         \
                const float wv = wlds[WB][r][p];                                   \
                acc.x = fmaf(wv, bk[p].x, acc.x);                                  \
                acc.y = fmaf(wv, bk[p].y, acc.y);                                  \
                acc.z = fmaf(wv, bk[p].z, acc.z);                                  \
                acc.w = fmaf(wv, bk[p].w, acc.w);                                  \
            }                                                                      \
            fx4 av; av.x = acc.x; av.y = acc.y; av.z = acc.z; av.w = acc.w;        \
            __builtin_nontemporal_store(av,                                        \
                &OO[((size_t)((GN) * GR + r) * BB + b) * DQ + tid]);               \
        }                                                                          \
    }

    // ---- prologue ----
    BURST(x0, 0)

    // g = 0
    BURST(x1, 1) PHASE1(x0, 0) BARRIER_RAW() FINALIZE(0)
    // g = 1
    BURST(x2, 2) PHASE1(x1, 1) BARRIER_RAW() FINALIZE(1) PHASE2(x0, 0, 0)
    // g = 2
    BURST(x0, 3) PHASE1(x2, 0) BARRIER_RAW() FINALIZE(0) PHASE2(x1, 1, 1)
    // g = 3
    BURST(x1, 4) PHASE1(x0, 1) BARRIER_RAW() FINALIZE(1) PHASE2(x2, 0, 2)
    // g = 4
    BURST(x2, 5) PHASE1(x1, 0) BARRIER_RAW() FINALIZE(0) PHASE2(x0, 1, 3)
    // g = 5
    BURST(x0, 6) PHASE1(x2, 1) BARRIER_RAW() FINALIZE(1) PHASE2(x1, 0, 4)
    // g = 6
    BURST(x1, 7) PHASE1(x0, 0) BARRIER_RAW() FINALIZE(0) PHASE2(x2, 1, 5)
    // g = 7
    PHASE1(x1, 1) BARRIER_RAW() FINALIZE(1) PHASE2(x0, 0, 6)
    // epilogue
    BARRIER_RAW() PHASE2(x1, 1, 7)

#undef PHASE2
#undef FINALIZE
#undef PHASE1
#undef BARRIER_RAW
#undef BURST
}

// ---------------------------------------------------------------------------
extern "C" void kernel_launch(void* const* d_in, const int* in_sizes, int n_in,
                              void* d_out, int out_size, void* d_ws, size_t ws_size,
                              hipStream_t stream) {
    const float* X     = (const float*)d_in[0];
    const float* task  = (const float*)d_in[1];
    const float* Wtok  = (const float*)d_in[2];
    const float* btok  = (const float*)d_in[3];
    const float* Wptok = (const float*)d_in[4];
    const float* bptok = (const float*)d_in[5];
    const float* gamma = (const float*)d_in[6];
    const float* beta  = (const float*)d_in[7];
    const float* Wnet  = (const float*)d_in[8];
    const float* bnet  = (const float*)d_in[9];
    float* out = (float*)d_out;

    float* ws = (float*)d_ws;
    float* bank = ws;                                  // B*P*D = 4,587,520
    float* ptok = bank + (size_t)BB * PP * DD;         // B*D   =   458,752
    float* GF   = ptok + (size_t)BB * DD;              // P*D   =    17,920
    float* SG   = GF + PP * DD;                        // P
    float* ZC   = SG + PP;                             // P

    prep_gf<<<PP, 256, 0, stream>>>(gamma, beta, Wnet, bnet, GF, SG, ZC);
    prep_bank<<<dim3(77, 8), 256, 0, stream>>>(task, Wtok, btok, Wptok, bptok, bank, ptok);
    fused_pipe<<<BB, 448, 0, stream>>>(X, bank, ptok, GF, SG, ZC, out);
}